// Round 1
// baseline (3997.969 us; speedup 1.0000x reference)
//
#include <hip/hip_runtime.h>
#include <cmath>

typedef _Float16 half8  __attribute__((ext_vector_type(8)));
typedef _Float16 half4v __attribute__((ext_vector_type(4)));
typedef float    float4v __attribute__((ext_vector_type(4)));

// async global->LDS, 16B per lane, wave-uniform LDS base (HW: base + lane*16)
__device__ __forceinline__ void gload_lds16(const _Float16* g, _Float16* l) {
    __builtin_amdgcn_global_load_lds(
        (const __attribute__((address_space(1))) void*)g,
        (__attribute__((address_space(3))) void*)l,
        16, 0, 0);
}

// ---------------------------------------------------------------------------
// MFMA conv3x3 (SAME), fp16 in / fp32 acc / fp16 out (relu).
// Wave tile = (MT*16) co x (NT*16) px; 4 waves stack on px (block = NT*64 px).
// R10: latency-bound fix (Mfma 22 / VALU 15 / Occ 20 all idle at P=150):
//   MT 8->4 (LDS 73728->36864 B => 4 blocks/CU; acc 96->48 AGPR) + NC x2,
//   weight staging via global_load_lds width=16 (no VGPR round-trip),
//   __launch_bounds__(256,4) => 16 waves/CU so staging stalls of one block
//   hide under the other 3 blocks' MFMA phases.
// Runtime dims (R6: templating CI bloats VGPR +23%); A via LDS read-order
// (0 bank conflicts); XCD swizzle keeps all sub-blocks of one patch/tile on
// one XCD (R5). R8's ping-pong + vmcnt(0) drain regressed (predictable: T4
// says counted-vmcnt is the gain; drain-0 is null) — TLP hiding used instead.
// MODE 0: att patch conv reading padded IMAGE directly; per-lane edge masks
//         emulate per-patch SAME zero-pad (validated R6/R8; kills g_patch).
// MODE 1: patch buffer [NB][26][26][CI] (ring zeroed).
// MODE 2: image [b][RSin][RSin][CI]; unit = b*64 + tile.
// ---------------------------------------------------------------------------
template<int MT, int NT, int MODE>
__global__ __launch_bounds__(256, 4)
void mfma_conv(const _Float16* __restrict__ in, const _Float16* __restrict__ Wg,
               const float* __restrict__ bias, _Float16* __restrict__ out,
               int CI, int CO, int RSin, int RSout, int NB, int NC, int p0)
{
    __shared__ __align__(16) _Float16 sW[9 * MT * 64 * 8];

    const int tid  = threadIdx.x;
    const int wave = tid >> 6;
    const int lane = tid & 63;
    const int ll   = lane & 15;
    const int quad = lane >> 4;

    const int NSUB = NC * (9 / NT);
    const int id   = blockIdx.x;
    const int xcd  = id & 7;
    const int slot = id >> 3;
    const int unit = (slot / NSUB) * 8 + xcd;
    const int rem  = slot % NSUB;
    const int pxb  = rem / NC;
    const int co_t = rem % NC;
    if (unit >= NB) return;
    const int co0 = co_t * (MT * 16);
    const int pbase = pxb * (NT * 64) + wave * (NT * 16);

    size_t in_base, out_base;
    int TY = 0, TX = 0;
    int b_off[NT], edge[NT];
    if (MODE == 0) {
        int pat = p0 + unit;
        int bb = pat / 225, remp = pat % 225;
        int pi = remp / 15, pj = remp % 15;
        in_base  = (size_t)bb * RSin * RSin * CI;
        out_base = (size_t)unit * 676 * CO;
        #pragma unroll
        for (int nt = 0; nt < NT; ++nt) {
            int p = pbase + nt * 16 + ll;
            int py = p / 24, px = p % 24;
            b_off[nt] = ((pi * 12 + py) * RSin + (pj * 12 + px)) * CI;
            edge[nt] = (py == 0 ? 1 : 0) | (py == 23 ? 2 : 0)
                     | (px == 0 ? 4 : 0) | (px == 23 ? 8 : 0);
        }
    } else if (MODE == 1) {
        in_base  = (size_t)unit * 676 * CI;
        out_base = (size_t)unit * 676 * CO;
        #pragma unroll
        for (int nt = 0; nt < NT; ++nt) {
            int p = pbase + nt * 16 + ll;
            b_off[nt] = ((p / 24) * RSin + (p % 24)) * CI;
            edge[nt] = 0;
        }
    } else {
        int tile = unit & 63, b = unit >> 6;
        TY = (tile >> 3) * 24; TX = (tile & 7) * 24;
        in_base  = (size_t)b * RSin * RSin * CI;
        out_base = (size_t)b * RSout * RSout * CO;
        #pragma unroll
        for (int nt = 0; nt < NT; ++nt) {
            int p = pbase + nt * 16 + ll;
            b_off[nt] = ((TY + p / 24) * RSin + (TX + p % 24)) * CI;
            edge[nt] = 0;
        }
    }

    float4v acc[MT][NT];
    #pragma unroll
    for (int mt = 0; mt < MT; ++mt)
        #pragma unroll
        for (int nt = 0; nt < NT; ++nt)
            acc[mt][nt] = (float4v){0.f, 0.f, 0.f, 0.f};

    for (int ci0 = 0; ci0 < CI; ci0 += 32) {
        __syncthreads();   // previous k-step's sW reads complete
        // stage 9*MT*64*16B of weights direct to LDS; layout is linear in
        // chunk index c so wave-uniform base + lane*16 lands correctly.
        #pragma unroll
        for (int it = 0; it < (9 * MT) / 4; ++it) {
            const int mtt = it * 4 + wave;          // wave-uniform chunk row
            const int mt = mtt % MT, t = mtt / MT;
            const _Float16* src =
                &Wg[((size_t)(co0 + mt * 16 + ll) * 9 + t) * CI + ci0 + quad * 8];
            gload_lds16(src, &sW[(size_t)(mtt * 64) * 8]);
        }
        __syncthreads();   // compiler drains vmcnt(0) here -> sW visible

        const _Float16* inp = in + in_base + ci0 + quad * 8;
        #pragma unroll
        for (int dy = 0; dy < 3; ++dy) {
            #pragma unroll
            for (int dx = 0; dx < 3; ++dx) {
                const int t = dy * 3 + dx;
                const int toff = (dy * RSin + dx) * CI;
                const int emask = (dy == 0 ? 1 : 0) | (dy == 2 ? 2 : 0)
                                | (dx == 0 ? 4 : 0) | (dx == 2 ? 8 : 0);
                half8 a[MT];
                #pragma unroll
                for (int mt = 0; mt < MT; ++mt)
                    a[mt] = *(const half8*)&sW[((t * MT + mt) * 64 + lane) * 8];
                #pragma unroll
                for (int nt = 0; nt < NT; ++nt) {
                    uint4 raw = *(const uint4*)(inp + b_off[nt] + toff);
                    if (MODE == 0) {
                        bool z = (edge[nt] & emask) != 0;
                        raw.x = z ? 0u : raw.x;
                        raw.y = z ? 0u : raw.y;
                        raw.z = z ? 0u : raw.z;
                        raw.w = z ? 0u : raw.w;
                    }
                    half8 b = *(half8*)&raw;
                    #pragma unroll
                    for (int mt = 0; mt < MT; ++mt)
                        acc[mt][nt] = __builtin_amdgcn_mfma_f32_16x16x32_f16(
                            a[mt], b, acc[mt][nt], 0, 0, 0);
                }
            }
        }
    }

    // epilogue: bias + relu -> fp16; D layout col=lane&15 (px), row=quad*4+reg
    #pragma unroll
    for (int mt = 0; mt < MT; ++mt) {
        float4v bs = *(const float4v*)&bias[co0 + mt * 16 + quad * 4];
        #pragma unroll
        for (int nt = 0; nt < NT; ++nt) {
            int p = pbase + nt * 16 + ll;
            size_t ooff = out_base
                + (size_t)((TY + p / 24 + 1) * RSout + (TX + p % 24) + 1) * CO
                + co0 + mt * 16 + quad * 4;
            float4v v = acc[mt][nt];
            half4v h;
            h.x = (_Float16)fmaxf(v.x + bs.x, 0.f);
            h.y = (_Float16)fmaxf(v.y + bs.y, 0.f);
            h.z = (_Float16)fmaxf(v.z + bs.z, 0.f);
            h.w = (_Float16)fmaxf(v.w + bs.w, 0.f);
            *(half4v*)(out + ooff) = h;
        }
    }
}

static inline int swiz_grid(int NB, int NC, int PXB) {
    return ((NB + 7) & ~7) * NC * PXB;
}

// ---------------------------------------------------------------------------
// M=1 conv3 via MFMA, CO padded to 16 (rows 1..15 zero). Runtime CI/RSI.
// NT n-tiles per wave, PXB px-blocks: grid = NB*PXB; unit = id/PXB.
// MODE 1: patch buffer [NB][26][26][CI]; ACT 1: sigmoid -> outp[unit*576+p]
// MODE 2: image [b][RSI][RSI][CI];       ACT 2: tanh    -> outp[b*36864+...]
// ---------------------------------------------------------------------------
template<int MODE, int ACT, int NT>
__global__ __launch_bounds__(256, 2)
void mfma_score(const _Float16* __restrict__ in, const _Float16* __restrict__ W16,
                const float* __restrict__ bias, float* __restrict__ outp,
                int CI, int RSI, int NB, int PXB)
{
    __shared__ __align__(16) _Float16 sW[9 * 16 * 32];

    const int tid  = threadIdx.x;
    const int wave = tid >> 6;
    const int lane = tid & 63;
    const int ll   = lane & 15;
    const int quad = lane >> 4;

    const int unit = blockIdx.x / PXB;
    const int pxb  = blockIdx.x % PXB;
    if (unit >= NB) return;
    const int pbase = pxb * (NT * 64) + wave * (NT * 16);

    size_t in_base;
    int ty = 0, tx = 0, bb = 0;
    if (MODE == 2) {
        bb = unit >> 6; int tile = unit & 63; ty = (tile >> 3) * 24; tx = (tile & 7) * 24;
        in_base = (size_t)bb * RSI * RSI * CI;
    } else {
        in_base = (size_t)unit * 676 * CI;
    }

    int b_off[NT];
    #pragma unroll
    for (int nt = 0; nt < NT; ++nt) {
        int p = pbase + nt * 16 + ll;
        b_off[nt] = ((ty + p / 24) * RSI + (tx + p % 24)) * CI;
    }

    float4v acc[NT];
    #pragma unroll
    for (int nt = 0; nt < NT; ++nt) acc[nt] = (float4v){0.f, 0.f, 0.f, 0.f};

    for (int ci0 = 0; ci0 < CI; ci0 += 32) {
        __syncthreads();
        for (int c = tid; c < 9 * 16 * 4; c += 256) {
            int q = c & 3, tco = c >> 2;
            int t = tco >> 4, co = tco & 15;
            *(uint4*)&sW[tco * 32 + q * 8] =
                *(const uint4*)&W16[((size_t)co * 9 + t) * CI + ci0 + q * 8];
        }
        __syncthreads();

        const _Float16* inp = in + in_base + ci0 + quad * 8;
        for (int dy = 0; dy < 3; ++dy)
            for (int dx = 0; dx < 3; ++dx) {
                const int t = dy * 3 + dx;
                const int toff = (dy * RSI + dx) * CI;
                half8 a = *(const half8*)&sW[(t * 16 + ll) * 32 + quad * 8];
                #pragma unroll
                for (int nt = 0; nt < NT; ++nt) {
                    half8 b = *(const half8*)(inp + b_off[nt] + toff);
                    acc[nt] = __builtin_amdgcn_mfma_f32_16x16x32_f16(a, b, acc[nt], 0, 0, 0);
                }
            }
    }

    if (quad == 0) {
        float bv = bias[0];
        #pragma unroll
        for (int nt = 0; nt < NT; ++nt) {
            int p = pbase + nt * 16 + ll;
            float v = acc[nt].x + bv;
            if (ACT == 1) {
                outp[(size_t)unit * 576 + p] = 1.f / (1.f + expf(-v));
            } else {
                int y = ty + p / 24, x = tx + p % 24;
                outp[(size_t)bb * 36864 + y * 192 + x] = tanhf(v);
            }
        }
    }
}

// ---------------------------------------------------------------------------
// helpers
// ---------------------------------------------------------------------------
__global__ __launch_bounds__(256)
void build_x16i(const float* __restrict__ src, const float* __restrict__ tgt,
                _Float16* __restrict__ X)
{
    int idx = blockIdx.x * 256 + threadIdx.x;
    int q = idx & 15, pid = idx >> 4;
    if (pid >= 2 * 36864) return;
    int b = pid / 36864, r = pid % 36864;
    int y = r / 192, x = r % 192;
    half8 h;
    #pragma unroll
    for (int j = 0; j < 8; ++j) {
        int ch = q * 8 + j;
        const float* im = (ch < 64) ? src : tgt;
        h[j] = (_Float16)im[(size_t)(b * 64 + (ch & 63)) * 36864 + r];
    }
    *(half8*)&X[(((size_t)b * 194 + y + 1) * 194 + (x + 1)) * 128 + q * 8] = h;
}

__global__ __launch_bounds__(256)
void cvt_w(const float* __restrict__ src, _Float16* __restrict__ dst, int CO, int CI)
{
    int idx = blockIdx.x * 256 + threadIdx.x;
    if (idx >= CO * 9 * CI) return;
    int ci = idx % CI, t = (idx / CI) % 9, co = idx / (9 * CI);
    dst[idx] = (_Float16)src[((size_t)co * CI + ci) * 9 + t];
}

__global__ __launch_bounds__(256)
void cvt_pad16(const float* __restrict__ src, _Float16* __restrict__ dst, int CI)
{
    int idx = blockIdx.x * 256 + threadIdx.x;
    if (idx >= 16 * 9 * CI) return;
    int ci = idx % CI, t = (idx / CI) % 9, co = idx / (9 * CI);
    dst[idx] = (co == 0) ? (_Float16)src[(size_t)ci * 9 + t] : (_Float16)0.0f;
}

__global__ __launch_bounds__(256)
void ring_zero(_Float16* __restrict__ buf, int npatch, int RS, int CI)
{
    int c8 = CI >> 3;
    int RC = 2 * RS + 2 * (RS - 2);
    int idx = blockIdx.x * 256 + threadIdx.x;
    if (idx >= npatch * RC * c8) return;
    int q = idx % c8, rp = (idx / c8) % RC, pl = idx / (c8 * RC);
    int r, c;
    if (rp < RS)            { r = 0;      c = rp; }
    else if (rp < 2 * RS)   { r = RS - 1; c = rp - RS; }
    else {
        int s = rp - 2 * RS, half = RS - 2;
        if (s < half) { r = s + 1;        c = 0; }
        else          { r = s - half + 1; c = RS - 1; }
    }
    uint4 z = {0u, 0u, 0u, 0u};
    *(uint4*)&buf[((size_t)pl * RS * RS + r * RS + c) * CI + q * 8] = z;
}

__global__ __launch_bounds__(256)
void att_finalize(const float* __restrict__ score, float* __restrict__ out)
{
    int idx = blockIdx.x * 256 + threadIdx.x;
    if (idx >= 2 * 36864) return;
    int b = idx / 36864, r = idx % 36864;
    int y = r / 192, x = r % 192;
    int i_lo = (y >= 24) ? (y - 12) / 12 : 0;
    int i_hi = min(14, y / 12);
    int j_lo = (x >= 24) ? (x - 12) / 12 : 0;
    int j_hi = min(14, x / 12);
    float s = 0.f; int cnt = 0;
    for (int i = i_lo; i <= i_hi; ++i)
        for (int j = j_lo; j <= j_hi; ++j) {
            s += score[(((size_t)b * 15 + i) * 15 + j) * 576 + (y - 12 * i) * 24 + (x - 12 * j)];
            ++cnt;
        }
    out[idx] = s / (float)cnt;
}

// ---------------------------------------------------------------------------
extern "C" void kernel_launch(void* const* d_in, const int* in_sizes, int n_in,
                              void* d_out, int out_size, void* d_ws, size_t ws_size,
                              hipStream_t stream)
{
    const float* src = (const float*)d_in[0];
    const float* tgt = (const float*)d_in[1];
    const float* W1  = (const float*)d_in[2];  const float* b1  = (const float*)d_in[3];
    const float* W2  = (const float*)d_in[4];  const float* b2  = (const float*)d_in[5];
    const float* W3  = (const float*)d_in[6];  const float* b3  = (const float*)d_in[7];
    const float* Wr1 = (const float*)d_in[8];  const float* br1 = (const float*)d_in[9];
    const float* Wr2 = (const float*)d_in[10]; const float* br2 = (const float*)d_in[11];
    const float* Wr3 = (const float*)d_in[12]; const float* br3 = (const float*)d_in[13];
    float* out = (float*)d_out;

    // ---- fixed workspace (halves) ----
    _Float16* ws = (_Float16*)d_ws;
    size_t o = 0;
    _Float16* X16i = ws + o; o += (size_t)2 * 194 * 194 * 128;
    _Float16* W1h  = ws + o; o += (size_t)512 * 9 * 128;
    _Float16* W2h  = ws + o; o += (size_t)256 * 9 * 512;
    _Float16* Wr1h = ws + o; o += (size_t)512 * 9 * 128;
    _Float16* Wr2h = ws + o; o += (size_t)64 * 9 * 512;
    _Float16* W3p  = ws + o; o += (size_t)16 * 9 * 256;
    _Float16* Wr3p = ws + o; o += (size_t)16 * 9 * 64;
    float*    score = (float*)(ws + o); o += 2 * 259200;
    const size_t fixed_h = o;

    // ---- adaptive patch chunking (no P1: conv1 reads the image, MODE0) ----
    const size_t per_patch_h = (size_t)676 * (512 + 256);        // 519,168
    const size_t regA_h = (size_t)2 * 194 * 194 * 512;
    const size_t regB_h = (size_t)2 * 194 * 194 * 64;
    size_t h_avail = ws_size / 2;
    int P = 50;
    {
        size_t n450 = 450 * per_patch_h; if (n450 < regA_h + regB_h) n450 = regA_h + regB_h;
        size_t n150 = 150 * per_patch_h; if (n150 < regA_h + regB_h) n150 = regA_h + regB_h;
        if (h_avail >= fixed_h + n450)      P = 450;
        else if (h_avail >= fixed_h + n150) P = 150;
    }
    const int nchunks = 450 / P;

    _Float16* D1 = ws + fixed_h;
    _Float16* D2 = D1 + (size_t)P * 676 * 512;

    // ---- precompute fp16 operands ----
    ring_zero<<<(2 * 772 * 16 + 255) / 256, 256, 0, stream>>>(X16i, 2, 194, 128);
    build_x16i<<<4608, 256, 0, stream>>>(src, tgt, X16i);
    cvt_w<<<2304, 256, 0, stream>>>(W1,  W1h,  512, 128);
    cvt_w<<<4608, 256, 0, stream>>>(W2,  W2h,  256, 512);
    cvt_w<<<2304, 256, 0, stream>>>(Wr1, Wr1h, 512, 128);
    cvt_w<<<1152, 256, 0, stream>>>(Wr2, Wr2h, 64,  512);
    cvt_pad16<<<(16 * 9 * 256 + 255) / 256, 256, 0, stream>>>(W3,  W3p,  256);
    cvt_pad16<<<(16 * 9 * 64  + 255) / 256, 256, 0, stream>>>(Wr3, Wr3p, 64);

    // ---- attention path ----
    ring_zero<<<(P * 100 * 64 + 255) / 256, 256, 0, stream>>>(D1, P, 26, 512);
    ring_zero<<<(P * 100 * 32 + 255) / 256, 256, 0, stream>>>(D2, P, 26, 256);
    for (int c = 0; c < nchunks; ++c) {
        int p0 = c * P;
        // conv1: 128->512 from padded image (MODE0), MT=4/NT=3, NC=8
        mfma_conv<4, 3, 0><<<swiz_grid(P, 8, 3), 256, 0, stream>>>(
            X16i, W1h, b1, D1, 128, 512, 194, 26, P, 8, p0);
        // conv2: 512->256 (MODE1), MT=4/NT=3, NC=4
        mfma_conv<4, 3, 1><<<swiz_grid(P, 4, 3), 256, 0, stream>>>(
            D1, W2h, b2, D2, 512, 256, 26, 26, P, 4, 0);
        // score: sigmoid, px-split x3
        mfma_score<1, 1, 3><<<P * 3, 256, 0, stream>>>(
            D2, W3p, b3, score + (size_t)p0 * 576, 256, 26, P, 3);
    }
    att_finalize<<<288, 256, 0, stream>>>(score, out + 73728);

    // ---- registration path (aliases chunk region; att chain complete) ----
    {
        _Float16* A1 = ws + fixed_h;
        _Float16* A2 = A1 + ((P >= 150) ? regA_h : (size_t)194 * 194 * 512);
        if (P >= 150) {
            ring_zero<<<(2 * 772 * 64 + 255) / 256, 256, 0, stream>>>(A1, 2, 194, 512);
            ring_zero<<<(2 * 772 * 8  + 255) / 256, 256, 0, stream>>>(A2, 2, 194, 64);
            mfma_conv<4, 3, 2><<<swiz_grid(128, 8, 3), 256, 0, stream>>>(
                X16i, Wr1h, br1, A1, 128, 512, 194, 194, 128, 8, 0);
            mfma_conv<4, 3, 2><<<swiz_grid(128, 1, 3), 256, 0, stream>>>(
                A1, Wr2h, br2, A2, 512, 64, 194, 194, 128, 1, 0);
            mfma_score<2, 2, 3><<<128 * 3, 256, 0, stream>>>(
                A2, Wr3p, br3, out, 64, 194, 128, 3);
        } else {
            for (int b = 0; b < 2; ++b) {
                ring_zero<<<(772 * 64 + 255) / 256, 256, 0, stream>>>(A1, 1, 194, 512);
                ring_zero<<<(772 * 8  + 255) / 256, 256, 0, stream>>>(A2, 1, 194, 64);
                mfma_conv<4, 3, 2><<<swiz_grid(64, 8, 3), 256, 0, stream>>>(
                    X16i + (size_t)b * 194 * 194 * 128, Wr1h, br1, A1,
                    128, 512, 194, 194, 64, 8, 0);
                mfma_conv<4, 3, 2><<<swiz_grid(64, 1, 3), 256, 0, stream>>>(
                    A1, Wr2h, br2, A2, 512, 64, 194, 194, 64, 1, 0);
                mfma_score<2, 2, 3><<<64 * 3, 256, 0, stream>>>(
                    A2, Wr3p, br3, out + (size_t)b * 36864, 64, 194, 64, 3);
            }
        }
    }
}

// Round 2
// 3061.068 us; speedup vs baseline: 1.3061x; 1.3061x over previous
//
#include <hip/hip_runtime.h>
#include <cmath>

typedef _Float16 half8  __attribute__((ext_vector_type(8)));
typedef _Float16 half4v __attribute__((ext_vector_type(4)));
typedef float    float4v __attribute__((ext_vector_type(4)));

// ---------------------------------------------------------------------------
// MFMA conv3x3 (SAME), fp16 in / fp32 acc / fp16 out (relu).
// Block tile = (COG*MT*16) co x (4*NT*16) px, COG*4 waves (COG co-groups x
// 4 px-groups). R11: R10's NC-doubling regressed 13x on HBM traffic (L2
// thrash: input re-read NC times; FETCH 69->531 MB, WRITE 43->993 MB).
// Keep R9 blocking (co-tile 128, input read 2x, sW 73728 B) and raise
// occupancy by widening the block instead: 8 waves @ MT=4 -> per-wave regs
// 48 AGPR + ~64 VGPR = 112 <= 128, launch_bounds(512,4) => 2 blocks/CU =
// 16 waves/CU (vs 8 in R9). Identical memory traffic to R9 by construction.
// Runtime dims (R6: templating CI bloats VGPR +23%); A via LDS read-order
// (0 bank conflicts); XCD swizzle keeps all sub-blocks of one unit on one
// XCD (R5). R8/R10: global_load_lds + vmcnt(0) drain regressed — two-barrier
// VGPR staging kept.
// MODE 0: att patch conv reading padded IMAGE directly; per-lane edge masks
//         emulate per-patch SAME zero-pad (validated R6/R8; kills g_patch).
// MODE 1: patch buffer [NB][26][26][CI] (ring zeroed).
// MODE 2: image [b][RSin][RSin][CI]; unit = b*64 + tile.
// ---------------------------------------------------------------------------
template<int MT, int COG, int NT, int MODE>
__global__ __launch_bounds__(256 * COG, COG == 2 ? 4 : 2)
void mfma_conv(const _Float16* __restrict__ in, const _Float16* __restrict__ Wg,
               const float* __restrict__ bias, _Float16* __restrict__ out,
               int CI, int CO, int RSin, int RSout, int NB, int NC, int p0)
{
    __shared__ __align__(16) _Float16 sW[9 * COG * MT * 64 * 8];

    const int tid  = threadIdx.x;
    const int wave = tid >> 6;
    const int lane = tid & 63;
    const int ll   = lane & 15;
    const int quad = lane >> 4;
    const int px_g = wave & 3;     // 4 px groups per block
    const int co_g = wave >> 2;    // COG co groups per block

    const int NSUB = NC * (9 / NT);
    const int id   = blockIdx.x;
    const int xcd  = id & 7;
    const int slot = id >> 3;
    const int unit = (slot / NSUB) * 8 + xcd;
    const int rem  = slot % NSUB;
    const int pxb  = rem / NC;
    const int co_t = rem % NC;
    if (unit >= NB) return;
    const int co0 = co_t * (COG * MT * 16);
    const int pbase = pxb * (NT * 64) + px_g * (NT * 16);

    size_t in_base, out_base;
    int TY = 0, TX = 0;
    int b_off[NT], edge[NT];
    if (MODE == 0) {
        int pat = p0 + unit;
        int bb = pat / 225, remp = pat % 225;
        int pi = remp / 15, pj = remp % 15;
        in_base  = (size_t)bb * RSin * RSin * CI;
        out_base = (size_t)unit * 676 * CO;
        #pragma unroll
        for (int nt = 0; nt < NT; ++nt) {
            int p = pbase + nt * 16 + ll;
            int py = p / 24, px = p % 24;
            b_off[nt] = ((pi * 12 + py) * RSin + (pj * 12 + px)) * CI;
            edge[nt] = (py == 0 ? 1 : 0) | (py == 23 ? 2 : 0)
                     | (px == 0 ? 4 : 0) | (px == 23 ? 8 : 0);
        }
    } else if (MODE == 1) {
        in_base  = (size_t)unit * 676 * CI;
        out_base = (size_t)unit * 676 * CO;
        #pragma unroll
        for (int nt = 0; nt < NT; ++nt) {
            int p = pbase + nt * 16 + ll;
            b_off[nt] = ((p / 24) * RSin + (p % 24)) * CI;
            edge[nt] = 0;
        }
    } else {
        int tile = unit & 63, b = unit >> 6;
        TY = (tile >> 3) * 24; TX = (tile & 7) * 24;
        in_base  = (size_t)b * RSin * RSin * CI;
        out_base = (size_t)b * RSout * RSout * CO;
        #pragma unroll
        for (int nt = 0; nt < NT; ++nt) {
            int p = pbase + nt * 16 + ll;
            b_off[nt] = ((TY + p / 24) * RSin + (TX + p % 24)) * CI;
            edge[nt] = 0;
        }
    }

    float4v acc[MT][NT];
    #pragma unroll
    for (int mt = 0; mt < MT; ++mt)
        #pragma unroll
        for (int nt = 0; nt < NT; ++nt)
            acc[mt][nt] = (float4v){0.f, 0.f, 0.f, 0.f};

    for (int ci0 = 0; ci0 < CI; ci0 += 32) {
        __syncthreads();
        for (int c = tid; c < 9 * COG * MT * 64; c += 256 * COG) {
            int lane_s = c & 63;
            int mtt = c >> 6;
            int mtb = mtt % (COG * MT), t = mtt / (COG * MT);
            *(uint4*)&sW[(size_t)c * 8] =
                *(const uint4*)&Wg[((size_t)(co0 + mtb * 16 + (lane_s & 15)) * 9 + t) * CI
                                   + ci0 + (lane_s >> 4) * 8];
        }
        __syncthreads();

        const _Float16* inp = in + in_base + ci0 + quad * 8;
        #pragma unroll
        for (int dy = 0; dy < 3; ++dy) {
            #pragma unroll
            for (int dx = 0; dx < 3; ++dx) {
                const int t = dy * 3 + dx;
                const int toff = (dy * RSin + dx) * CI;
                const int emask = (dy == 0 ? 1 : 0) | (dy == 2 ? 2 : 0)
                                | (dx == 0 ? 4 : 0) | (dx == 2 ? 8 : 0);
                half8 a[MT];
                #pragma unroll
                for (int mt = 0; mt < MT; ++mt)
                    a[mt] = *(const half8*)&sW[((t * (COG * MT) + co_g * MT + mt) * 64
                                               + lane) * 8];
                #pragma unroll
                for (int nt = 0; nt < NT; ++nt) {
                    uint4 raw = *(const uint4*)(inp + b_off[nt] + toff);
                    if (MODE == 0) {
                        bool z = (edge[nt] & emask) != 0;
                        raw.x = z ? 0u : raw.x;
                        raw.y = z ? 0u : raw.y;
                        raw.z = z ? 0u : raw.z;
                        raw.w = z ? 0u : raw.w;
                    }
                    half8 b = *(half8*)&raw;
                    #pragma unroll
                    for (int mt = 0; mt < MT; ++mt)
                        acc[mt][nt] = __builtin_amdgcn_mfma_f32_16x16x32_f16(
                            a[mt], b, acc[mt][nt], 0, 0, 0);
                }
            }
        }
    }

    // epilogue: bias + relu -> fp16; D layout col=lane&15 (px), row=quad*4+reg
    #pragma unroll
    for (int mt = 0; mt < MT; ++mt) {
        float4v bs = *(const float4v*)&bias[co0 + (co_g * MT + mt) * 16 + quad * 4];
        #pragma unroll
        for (int nt = 0; nt < NT; ++nt) {
            int p = pbase + nt * 16 + ll;
            size_t ooff = out_base
                + (size_t)((TY + p / 24 + 1) * RSout + (TX + p % 24) + 1) * CO
                + co0 + (co_g * MT + mt) * 16 + quad * 4;
            float4v v = acc[mt][nt];
            half4v h;
            h.x = (_Float16)fmaxf(v.x + bs.x, 0.f);
            h.y = (_Float16)fmaxf(v.y + bs.y, 0.f);
            h.z = (_Float16)fmaxf(v.z + bs.z, 0.f);
            h.w = (_Float16)fmaxf(v.w + bs.w, 0.f);
            *(half4v*)(out + ooff) = h;
        }
    }
}

static inline int swiz_grid(int NB, int NC, int PXB) {
    return ((NB + 7) & ~7) * NC * PXB;
}

// ---------------------------------------------------------------------------
// M=1 conv3 via MFMA, CO padded to 16 (rows 1..15 zero). Runtime CI/RSI.
// NT n-tiles per wave, PXB px-blocks: grid = NB*PXB; unit = id/PXB.
// MODE 1: patch buffer [NB][26][26][CI]; ACT 1: sigmoid -> outp[unit*576+p]
// MODE 2: image [b][RSI][RSI][CI];       ACT 2: tanh    -> outp[b*36864+...]
// ---------------------------------------------------------------------------
template<int MODE, int ACT, int NT>
__global__ __launch_bounds__(256, 2)
void mfma_score(const _Float16* __restrict__ in, const _Float16* __restrict__ W16,
                const float* __restrict__ bias, float* __restrict__ outp,
                int CI, int RSI, int NB, int PXB)
{
    __shared__ __align__(16) _Float16 sW[9 * 16 * 32];

    const int tid  = threadIdx.x;
    const int wave = tid >> 6;
    const int lane = tid & 63;
    const int ll   = lane & 15;
    const int quad = lane >> 4;

    const int unit = blockIdx.x / PXB;
    const int pxb  = blockIdx.x % PXB;
    if (unit >= NB) return;
    const int pbase = pxb * (NT * 64) + wave * (NT * 16);

    size_t in_base;
    int ty = 0, tx = 0, bb = 0;
    if (MODE == 2) {
        bb = unit >> 6; int tile = unit & 63; ty = (tile >> 3) * 24; tx = (tile & 7) * 24;
        in_base = (size_t)bb * RSI * RSI * CI;
    } else {
        in_base = (size_t)unit * 676 * CI;
    }

    int b_off[NT];
    #pragma unroll
    for (int nt = 0; nt < NT; ++nt) {
        int p = pbase + nt * 16 + ll;
        b_off[nt] = ((ty + p / 24) * RSI + (tx + p % 24)) * CI;
    }

    float4v acc[NT];
    #pragma unroll
    for (int nt = 0; nt < NT; ++nt) acc[nt] = (float4v){0.f, 0.f, 0.f, 0.f};

    for (int ci0 = 0; ci0 < CI; ci0 += 32) {
        __syncthreads();
        for (int c = tid; c < 9 * 16 * 4; c += 256) {
            int q = c & 3, tco = c >> 2;
            int t = tco >> 4, co = tco & 15;
            *(uint4*)&sW[tco * 32 + q * 8] =
                *(const uint4*)&W16[((size_t)co * 9 + t) * CI + ci0 + q * 8];
        }
        __syncthreads();

        const _Float16* inp = in + in_base + ci0 + quad * 8;
        for (int dy = 0; dy < 3; ++dy)
            for (int dx = 0; dx < 3; ++dx) {
                const int t = dy * 3 + dx;
                const int toff = (dy * RSI + dx) * CI;
                half8 a = *(const half8*)&sW[(t * 16 + ll) * 32 + quad * 8];
                #pragma unroll
                for (int nt = 0; nt < NT; ++nt) {
                    half8 b = *(const half8*)(inp + b_off[nt] + toff);
                    acc[nt] = __builtin_amdgcn_mfma_f32_16x16x32_f16(a, b, acc[nt], 0, 0, 0);
                }
            }
    }

    if (quad == 0) {
        float bv = bias[0];
        #pragma unroll
        for (int nt = 0; nt < NT; ++nt) {
            int p = pbase + nt * 16 + ll;
            float v = acc[nt].x + bv;
            if (ACT == 1) {
                outp[(size_t)unit * 576 + p] = 1.f / (1.f + expf(-v));
            } else {
                int y = ty + p / 24, x = tx + p % 24;
                outp[(size_t)bb * 36864 + y * 192 + x] = tanhf(v);
            }
        }
    }
}

// ---------------------------------------------------------------------------
// helpers
// ---------------------------------------------------------------------------
__global__ __launch_bounds__(256)
void build_x16i(const float* __restrict__ src, const float* __restrict__ tgt,
                _Float16* __restrict__ X)
{
    int idx = blockIdx.x * 256 + threadIdx.x;
    int q = idx & 15, pid = idx >> 4;
    if (pid >= 2 * 36864) return;
    int b = pid / 36864, r = pid % 36864;
    int y = r / 192, x = r % 192;
    half8 h;
    #pragma unroll
    for (int j = 0; j < 8; ++j) {
        int ch = q * 8 + j;
        const float* im = (ch < 64) ? src : tgt;
        h[j] = (_Float16)im[(size_t)(b * 64 + (ch & 63)) * 36864 + r];
    }
    *(half8*)&X[(((size_t)b * 194 + y + 1) * 194 + (x + 1)) * 128 + q * 8] = h;
}

__global__ __launch_bounds__(256)
void cvt_w(const float* __restrict__ src, _Float16* __restrict__ dst, int CO, int CI)
{
    int idx = blockIdx.x * 256 + threadIdx.x;
    if (idx >= CO * 9 * CI) return;
    int ci = idx % CI, t = (idx / CI) % 9, co = idx / (9 * CI);
    dst[idx] = (_Float16)src[((size_t)co * CI + ci) * 9 + t];
}

__global__ __launch_bounds__(256)
void cvt_pad16(const float* __restrict__ src, _Float16* __restrict__ dst, int CI)
{
    int idx = blockIdx.x * 256 + threadIdx.x;
    if (idx >= 16 * 9 * CI) return;
    int ci = idx % CI, t = (idx / CI) % 9, co = idx / (9 * CI);
    dst[idx] = (co == 0) ? (_Float16)src[(size_t)ci * 9 + t] : (_Float16)0.0f;
}

__global__ __launch_bounds__(256)
void ring_zero(_Float16* __restrict__ buf, int npatch, int RS, int CI)
{
    int c8 = CI >> 3;
    int RC = 2 * RS + 2 * (RS - 2);
    int idx = blockIdx.x * 256 + threadIdx.x;
    if (idx >= npatch * RC * c8) return;
    int q = idx % c8, rp = (idx / c8) % RC, pl = idx / (c8 * RC);
    int r, c;
    if (rp < RS)            { r = 0;      c = rp; }
    else if (rp < 2 * RS)   { r = RS - 1; c = rp - RS; }
    else {
        int s = rp - 2 * RS, half = RS - 2;
        if (s < half) { r = s + 1;        c = 0; }
        else          { r = s - half + 1; c = RS - 1; }
    }
    uint4 z = {0u, 0u, 0u, 0u};
    *(uint4*)&buf[((size_t)pl * RS * RS + r * RS + c) * CI + q * 8] = z;
}

__global__ __launch_bounds__(256)
void att_finalize(const float* __restrict__ score, float* __restrict__ out)
{
    int idx = blockIdx.x * 256 + threadIdx.x;
    if (idx >= 2 * 36864) return;
    int b = idx / 36864, r = idx % 36864;
    int y = r / 192, x = r % 192;
    int i_lo = (y >= 24) ? (y - 12) / 12 : 0;
    int i_hi = min(14, y / 12);
    int j_lo = (x >= 24) ? (x - 12) / 12 : 0;
    int j_hi = min(14, x / 12);
    float s = 0.f; int cnt = 0;
    for (int i = i_lo; i <= i_hi; ++i)
        for (int j = j_lo; j <= j_hi; ++j) {
            s += score[(((size_t)b * 15 + i) * 15 + j) * 576 + (y - 12 * i) * 24 + (x - 12 * j)];
            ++cnt;
        }
    out[idx] = s / (float)cnt;
}

// ---------------------------------------------------------------------------
extern "C" void kernel_launch(void* const* d_in, const int* in_sizes, int n_in,
                              void* d_out, int out_size, void* d_ws, size_t ws_size,
                              hipStream_t stream)
{
    const float* src = (const float*)d_in[0];
    const float* tgt = (const float*)d_in[1];
    const float* W1  = (const float*)d_in[2];  const float* b1  = (const float*)d_in[3];
    const float* W2  = (const float*)d_in[4];  const float* b2  = (const float*)d_in[5];
    const float* W3  = (const float*)d_in[6];  const float* b3  = (const float*)d_in[7];
    const float* Wr1 = (const float*)d_in[8];  const float* br1 = (const float*)d_in[9];
    const float* Wr2 = (const float*)d_in[10]; const float* br2 = (const float*)d_in[11];
    const float* Wr3 = (const float*)d_in[12]; const float* br3 = (const float*)d_in[13];
    float* out = (float*)d_out;

    // ---- fixed workspace (halves) ----
    _Float16* ws = (_Float16*)d_ws;
    size_t o = 0;
    _Float16* X16i = ws + o; o += (size_t)2 * 194 * 194 * 128;
    _Float16* W1h  = ws + o; o += (size_t)512 * 9 * 128;
    _Float16* W2h  = ws + o; o += (size_t)256 * 9 * 512;
    _Float16* Wr1h = ws + o; o += (size_t)512 * 9 * 128;
    _Float16* Wr2h = ws + o; o += (size_t)64 * 9 * 512;
    _Float16* W3p  = ws + o; o += (size_t)16 * 9 * 256;
    _Float16* Wr3p = ws + o; o += (size_t)16 * 9 * 64;
    float*    score = (float*)(ws + o); o += 2 * 259200;
    const size_t fixed_h = o;

    // ---- adaptive patch chunking (no P1: conv1 reads the image, MODE0) ----
    const size_t per_patch_h = (size_t)676 * (512 + 256);        // 519,168
    const size_t regA_h = (size_t)2 * 194 * 194 * 512;
    const size_t regB_h = (size_t)2 * 194 * 194 * 64;
    size_t h_avail = ws_size / 2;
    int P = 50;
    {
        size_t n450 = 450 * per_patch_h; if (n450 < regA_h + regB_h) n450 = regA_h + regB_h;
        size_t n150 = 150 * per_patch_h; if (n150 < regA_h + regB_h) n150 = regA_h + regB_h;
        if (h_avail >= fixed_h + n450)      P = 450;
        else if (h_avail >= fixed_h + n150) P = 150;
    }
    const int nchunks = 450 / P;

    _Float16* D1 = ws + fixed_h;
    _Float16* D2 = D1 + (size_t)P * 676 * 512;

    // ---- precompute fp16 operands ----
    ring_zero<<<(2 * 772 * 16 + 255) / 256, 256, 0, stream>>>(X16i, 2, 194, 128);
    build_x16i<<<4608, 256, 0, stream>>>(src, tgt, X16i);
    cvt_w<<<2304, 256, 0, stream>>>(W1,  W1h,  512, 128);
    cvt_w<<<4608, 256, 0, stream>>>(W2,  W2h,  256, 512);
    cvt_w<<<2304, 256, 0, stream>>>(Wr1, Wr1h, 512, 128);
    cvt_w<<<1152, 256, 0, stream>>>(Wr2, Wr2h, 64,  512);
    cvt_pad16<<<(16 * 9 * 256 + 255) / 256, 256, 0, stream>>>(W3,  W3p,  256);
    cvt_pad16<<<(16 * 9 * 64  + 255) / 256, 256, 0, stream>>>(Wr3, Wr3p, 64);

    // ---- attention path ----
    ring_zero<<<(P * 100 * 64 + 255) / 256, 256, 0, stream>>>(D1, P, 26, 512);
    ring_zero<<<(P * 100 * 32 + 255) / 256, 256, 0, stream>>>(D2, P, 26, 256);
    for (int c = 0; c < nchunks; ++c) {
        int p0 = c * P;
        // conv1: 128->512 from padded image (MODE0), 8 waves (2co x 4px), NC=4
        mfma_conv<4, 2, 3, 0><<<swiz_grid(P, 4, 3), 512, 0, stream>>>(
            X16i, W1h, b1, D1, 128, 512, 194, 26, P, 4, p0);
        // conv2: 512->256 (MODE1), 8 waves (2co x 4px), NC=2
        mfma_conv<4, 2, 3, 1><<<swiz_grid(P, 2, 3), 512, 0, stream>>>(
            D1, W2h, b2, D2, 512, 256, 26, 26, P, 2, 0);
        // score: sigmoid, px-split x3
        mfma_score<1, 1, 3><<<P * 3, 256, 0, stream>>>(
            D2, W3p, b3, score + (size_t)p0 * 576, 256, 26, P, 3);
    }
    att_finalize<<<288, 256, 0, stream>>>(score, out + 73728);

    // ---- registration path (aliases chunk region; att chain complete) ----
    {
        _Float16* A1 = ws + fixed_h;
        _Float16* A2 = A1 + ((P >= 150) ? regA_h : (size_t)194 * 194 * 512);
        if (P >= 150) {
            ring_zero<<<(2 * 772 * 64 + 255) / 256, 256, 0, stream>>>(A1, 2, 194, 512);
            ring_zero<<<(2 * 772 * 8  + 255) / 256, 256, 0, stream>>>(A2, 2, 194, 64);
            mfma_conv<4, 2, 3, 2><<<swiz_grid(128, 4, 3), 512, 0, stream>>>(
                X16i, Wr1h, br1, A1, 128, 512, 194, 194, 128, 4, 0);
            mfma_conv<4, 1, 3, 2><<<swiz_grid(128, 1, 3), 256, 0, stream>>>(
                A1, Wr2h, br2, A2, 512, 64, 194, 194, 128, 1, 0);
            mfma_score<2, 2, 3><<<128 * 3, 256, 0, stream>>>(
                A2, Wr3p, br3, out, 64, 194, 128, 3);
        } else {
            for (int b = 0; b < 2; ++b) {
                ring_zero<<<(772 * 64 + 255) / 256, 256, 0, stream>>>(A1, 1, 194, 512);
                ring_zero<<<(772 * 8  + 255) / 256, 256, 0, stream>>>(A2, 1, 194, 64);
                mfma_conv<4, 2, 3, 2><<<swiz_grid(64, 4, 3), 512, 0, stream>>>(
                    X16i + (size_t)b * 194 * 194 * 128, Wr1h, br1, A1,
                    128, 512, 194, 194, 64, 4, 0);
                mfma_conv<4, 1, 3, 2><<<swiz_grid(64, 1, 3), 256, 0, stream>>>(
                    A1, Wr2h, br2, A2, 512, 64, 194, 194, 64, 1, 0);
                mfma_score<2, 2, 3><<<64 * 3, 256, 0, stream>>>(
                    A2, Wr3p, br3, out + (size_t)b * 36864, 64, 194, 64, 3);
            }
        }
    }
}

// Round 3
// 2759.221 us; speedup vs baseline: 1.4489x; 1.1094x over previous
//
#include <hip/hip_runtime.h>
#include <cmath>

typedef _Float16 half8  __attribute__((ext_vector_type(8)));
typedef _Float16 half4v __attribute__((ext_vector_type(4)));
typedef float    float4v __attribute__((ext_vector_type(4)));

// ---------------------------------------------------------------------------
// MFMA conv3x3 (SAME), fp16 in / fp32 acc / fp16 out (relu).
// R12 structure: FULL-PATCH blocks. WAVES waves all stacked on px, each wave
// MT=4 co-rows x NT=3 px-frags => block = 64 co x (WAVES*48) px.
//   - Weight staging amortization: 36864 B per K-step per 576 px = 64 B/px
//     (R0/R9 structure paid 384 B/px => L2 feed was ~50% of MFMA time).
//   - sW double-buffered via global_load_lds issued BEFORE compute, ONE
//     __syncthreads per K-step (drains vmcnt) — catalog T3-minimum. R8's
//     failure was drain-right-after-issue; here latency hides under MFMA.
//   - NC co-tiles share a unit's input: adjacent block ids => same XCD,
//     1 block/CU, per-K-step slice 43 KB x ~4-8 units/XCD => L2-resident.
//     (R10 lesson: small blocks x 4/CU x NC=4 drifted => 13x HBM traffic.)
//   - R11 lesson: never duplicate b-loads across co-groups in one block.
// Regs: acc 48 AGPR + ~60 VGPR => 3 waves/SIMD (launch_bounds(W*64,3)).
// MODE 0: att conv1 reads padded IMAGE; per-lane edge masks emulate per-patch
//         SAME zero-pad. MODE 1: patch buffer [NB][26][26][CI] (ring zeroed).
// MODE 2: image [b][RSin][RSin][CI]; unit = b*64 + tile.
// ---------------------------------------------------------------------------
template<int WAVES, int NT, int MODE>
__global__ __launch_bounds__(WAVES * 64, 3)
void mfma_conv(const _Float16* __restrict__ in, const _Float16* __restrict__ Wg,
               const float* __restrict__ bias, _Float16* __restrict__ out,
               int CI, int CO, int RSin, int RSout, int NB, int NC, int PXB, int p0)
{
    constexpr int MT = 4;
    constexpr int THREADS = WAVES * 64;
    constexpr int CHUNKS = 9 * MT * 64;              // 16B chunks per buffer
    __shared__ __align__(16) _Float16 sW[2][CHUNKS * 8];

    const int tid  = threadIdx.x;
    const int wave = tid >> 6;
    const int lane = tid & 63;
    const int ll   = lane & 15;
    const int quad = lane >> 4;

    const int NSUB = NC * PXB;
    const int id   = blockIdx.x;
    const int xcd  = id & 7;
    const int slot = id >> 3;
    const int unit = (slot / NSUB) * 8 + xcd;
    const int rem  = slot % NSUB;
    const int pxb  = rem / NC;
    const int co_t = rem % NC;
    if (unit >= NB) return;
    const int co0 = co_t * (MT * 16);
    const int pbase = (pxb * WAVES + wave) * (NT * 16);

    size_t in_base, out_base;
    int TY = 0, TX = 0;
    int b_off[NT], edge[NT];
    if (MODE == 0) {
        int pat = p0 + unit;
        int bb = pat / 225, remp = pat % 225;
        int pi = remp / 15, pj = remp % 15;
        in_base  = (size_t)bb * RSin * RSin * CI;
        out_base = (size_t)unit * 676 * CO;
        #pragma unroll
        for (int nt = 0; nt < NT; ++nt) {
            int p = pbase + nt * 16 + ll;
            int py = p / 24, px = p % 24;
            b_off[nt] = ((pi * 12 + py) * RSin + (pj * 12 + px)) * CI;
            edge[nt] = (py == 0 ? 1 : 0) | (py == 23 ? 2 : 0)
                     | (px == 0 ? 4 : 0) | (px == 23 ? 8 : 0);
        }
    } else if (MODE == 1) {
        in_base  = (size_t)unit * 676 * CI;
        out_base = (size_t)unit * 676 * CO;
        #pragma unroll
        for (int nt = 0; nt < NT; ++nt) {
            int p = pbase + nt * 16 + ll;
            b_off[nt] = ((p / 24) * RSin + (p % 24)) * CI;
            edge[nt] = 0;
        }
    } else {
        int tile = unit & 63, b = unit >> 6;
        TY = (tile >> 3) * 24; TX = (tile & 7) * 24;
        in_base  = (size_t)b * RSin * RSin * CI;
        out_base = (size_t)b * RSout * RSout * CO;
        #pragma unroll
        for (int nt = 0; nt < NT; ++nt) {
            int p = pbase + nt * 16 + ll;
            b_off[nt] = ((TY + p / 24) * RSin + (TX + p % 24)) * CI;
            edge[nt] = 0;
        }
    }

    // stage one 32-ci weight slice into sW[buf] (async, no VGPR round-trip)
    auto stage = [&](int buf, int ci0) {
        #pragma unroll
        for (int k = 0; k < CHUNKS / THREADS; ++k) {
            int c = tid + k * THREADS;
            int lane_s = c & 63;
            int mtt = c >> 6;
            int mt = mtt & (MT - 1), t = mtt / MT;
            const _Float16* src =
                &Wg[((size_t)(co0 + mt * 16 + (lane_s & 15)) * 9 + t) * CI
                    + ci0 + (lane_s >> 4) * 8];
            __builtin_amdgcn_global_load_lds(
                (const __attribute__((address_space(1))) void*)src,
                (__attribute__((address_space(3))) void*)&sW[buf][(size_t)c * 8],
                16, 0, 0);
        }
    };

    float4v acc[MT][NT];
    #pragma unroll
    for (int mt = 0; mt < MT; ++mt)
        #pragma unroll
        for (int nt = 0; nt < NT; ++nt)
            acc[mt][nt] = (float4v){0.f, 0.f, 0.f, 0.f};

    stage(0, 0);
    __syncthreads();                 // prologue buffer ready

    int buf = 0;
    for (int ci0 = 0; ci0 < CI; ci0 += 32) {
        if (ci0 + 32 < CI) stage(buf ^ 1, ci0 + 32);   // overlap w/ compute

        const _Float16* inp = in + in_base + ci0 + quad * 8;
        #pragma unroll
        for (int dy = 0; dy < 3; ++dy) {
            #pragma unroll
            for (int dx = 0; dx < 3; ++dx) {
                const int t = dy * 3 + dx;
                const int toff = (dy * RSin + dx) * CI;
                const int emask = (dy == 0 ? 1 : 0) | (dy == 2 ? 2 : 0)
                                | (dx == 0 ? 4 : 0) | (dx == 2 ? 8 : 0);
                half8 a[MT];
                #pragma unroll
                for (int mt = 0; mt < MT; ++mt)
                    a[mt] = *(const half8*)&sW[buf][((t * MT + mt) * 64 + lane) * 8];
                #pragma unroll
                for (int nt = 0; nt < NT; ++nt) {
                    uint4 raw = *(const uint4*)(inp + b_off[nt] + toff);
                    if (MODE == 0) {
                        bool z = (edge[nt] & emask) != 0;
                        raw.x = z ? 0u : raw.x;
                        raw.y = z ? 0u : raw.y;
                        raw.z = z ? 0u : raw.z;
                        raw.w = z ? 0u : raw.w;
                    }
                    half8 b = *(half8*)&raw;
                    #pragma unroll
                    for (int mt = 0; mt < MT; ++mt)
                        acc[mt][nt] = __builtin_amdgcn_mfma_f32_16x16x32_f16(
                            a[mt], b, acc[mt][nt], 0, 0, 0);
                }
            }
        }
        __syncthreads();             // drains vmcnt(0): staged loads landed,
        buf ^= 1;                    // and all waves done reading sW[buf]
    }

    // epilogue: bias + relu -> fp16; D layout col=lane&15 (px), row=quad*4+reg
    #pragma unroll
    for (int mt = 0; mt < MT; ++mt) {
        float4v bs = *(const float4v*)&bias[co0 + mt * 16 + quad * 4];
        #pragma unroll
        for (int nt = 0; nt < NT; ++nt) {
            int p = pbase + nt * 16 + ll;
            size_t ooff = out_base
                + (size_t)((TY + p / 24 + 1) * RSout + (TX + p % 24) + 1) * CO
                + co0 + mt * 16 + quad * 4;
            float4v v = acc[mt][nt];
            half4v h;
            h.x = (_Float16)fmaxf(v.x + bs.x, 0.f);
            h.y = (_Float16)fmaxf(v.y + bs.y, 0.f);
            h.z = (_Float16)fmaxf(v.z + bs.z, 0.f);
            h.w = (_Float16)fmaxf(v.w + bs.w, 0.f);
            *(half4v*)(out + ooff) = h;
        }
    }
}

static inline int swiz_grid(int NB, int NC, int PXB) {
    return ((NB + 7) & ~7) * NC * PXB;
}

// ---------------------------------------------------------------------------
// M=1 conv3 via MFMA, CO padded to 16 (rows 1..15 zero). Runtime CI/RSI.
// NT n-tiles per wave, PXB px-blocks: grid = NB*PXB; unit = id/PXB.
// MODE 1: patch buffer [NB][26][26][CI]; ACT 1: sigmoid -> outp[unit*576+p]
// MODE 2: image [b][RSI][RSI][CI];       ACT 2: tanh    -> outp[b*36864+...]
// ---------------------------------------------------------------------------
template<int MODE, int ACT, int NT>
__global__ __launch_bounds__(256, 2)
void mfma_score(const _Float16* __restrict__ in, const _Float16* __restrict__ W16,
                const float* __restrict__ bias, float* __restrict__ outp,
                int CI, int RSI, int NB, int PXB)
{
    __shared__ __align__(16) _Float16 sW[9 * 16 * 32];

    const int tid  = threadIdx.x;
    const int wave = tid >> 6;
    const int lane = tid & 63;
    const int ll   = lane & 15;
    const int quad = lane >> 4;

    const int unit = blockIdx.x / PXB;
    const int pxb  = blockIdx.x % PXB;
    if (unit >= NB) return;
    const int pbase = pxb * (NT * 64) + wave * (NT * 16);

    size_t in_base;
    int ty = 0, tx = 0, bb = 0;
    if (MODE == 2) {
        bb = unit >> 6; int tile = unit & 63; ty = (tile >> 3) * 24; tx = (tile & 7) * 24;
        in_base = (size_t)bb * RSI * RSI * CI;
    } else {
        in_base = (size_t)unit * 676 * CI;
    }

    int b_off[NT];
    #pragma unroll
    for (int nt = 0; nt < NT; ++nt) {
        int p = pbase + nt * 16 + ll;
        b_off[nt] = ((ty + p / 24) * RSI + (tx + p % 24)) * CI;
    }

    float4v acc[NT];
    #pragma unroll
    for (int nt = 0; nt < NT; ++nt) acc[nt] = (float4v){0.f, 0.f, 0.f, 0.f};

    for (int ci0 = 0; ci0 < CI; ci0 += 32) {
        __syncthreads();
        for (int c = tid; c < 9 * 16 * 4; c += 256) {
            int q = c & 3, tco = c >> 2;
            int t = tco >> 4, co = tco & 15;
            *(uint4*)&sW[tco * 32 + q * 8] =
                *(const uint4*)&W16[((size_t)co * 9 + t) * CI + ci0 + q * 8];
        }
        __syncthreads();

        const _Float16* inp = in + in_base + ci0 + quad * 8;
        for (int dy = 0; dy < 3; ++dy)
            for (int dx = 0; dx < 3; ++dx) {
                const int t = dy * 3 + dx;
                const int toff = (dy * RSI + dx) * CI;
                half8 a = *(const half8*)&sW[(t * 16 + ll) * 32 + quad * 8];
                #pragma unroll
                for (int nt = 0; nt < NT; ++nt) {
                    half8 b = *(const half8*)(inp + b_off[nt] + toff);
                    acc[nt] = __builtin_amdgcn_mfma_f32_16x16x32_f16(a, b, acc[nt], 0, 0, 0);
                }
            }
    }

    if (quad == 0) {
        float bv = bias[0];
        #pragma unroll
        for (int nt = 0; nt < NT; ++nt) {
            int p = pbase + nt * 16 + ll;
            float v = acc[nt].x + bv;
            if (ACT == 1) {
                outp[(size_t)unit * 576 + p] = 1.f / (1.f + expf(-v));
            } else {
                int y = ty + p / 24, x = tx + p % 24;
                outp[(size_t)bb * 36864 + y * 192 + x] = tanhf(v);
            }
        }
    }
}

// ---------------------------------------------------------------------------
// helpers
// ---------------------------------------------------------------------------
__global__ __launch_bounds__(256)
void build_x16i(const float* __restrict__ src, const float* __restrict__ tgt,
                _Float16* __restrict__ X)
{
    int idx = blockIdx.x * 256 + threadIdx.x;
    int q = idx & 15, pid = idx >> 4;
    if (pid >= 2 * 36864) return;
    int b = pid / 36864, r = pid % 36864;
    int y = r / 192, x = r % 192;
    half8 h;
    #pragma unroll
    for (int j = 0; j < 8; ++j) {
        int ch = q * 8 + j;
        const float* im = (ch < 64) ? src : tgt;
        h[j] = (_Float16)im[(size_t)(b * 64 + (ch & 63)) * 36864 + r];
    }
    *(half8*)&X[(((size_t)b * 194 + y + 1) * 194 + (x + 1)) * 128 + q * 8] = h;
}

__global__ __launch_bounds__(256)
void cvt_w(const float* __restrict__ src, _Float16* __restrict__ dst, int CO, int CI)
{
    int idx = blockIdx.x * 256 + threadIdx.x;
    if (idx >= CO * 9 * CI) return;
    int ci = idx % CI, t = (idx / CI) % 9, co = idx / (9 * CI);
    dst[idx] = (_Float16)src[((size_t)co * CI + ci) * 9 + t];
}

__global__ __launch_bounds__(256)
void cvt_pad16(const float* __restrict__ src, _Float16* __restrict__ dst, int CI)
{
    int idx = blockIdx.x * 256 + threadIdx.x;
    if (idx >= 16 * 9 * CI) return;
    int ci = idx % CI, t = (idx / CI) % 9, co = idx / (9 * CI);
    dst[idx] = (co == 0) ? (_Float16)src[(size_t)ci * 9 + t] : (_Float16)0.0f;
}

__global__ __launch_bounds__(256)
void ring_zero(_Float16* __restrict__ buf, int npatch, int RS, int CI)
{
    int c8 = CI >> 3;
    int RC = 2 * RS + 2 * (RS - 2);
    int idx = blockIdx.x * 256 + threadIdx.x;
    if (idx >= npatch * RC * c8) return;
    int q = idx % c8, rp = (idx / c8) % RC, pl = idx / (c8 * RC);
    int r, c;
    if (rp < RS)            { r = 0;      c = rp; }
    else if (rp < 2 * RS)   { r = RS - 1; c = rp - RS; }
    else {
        int s = rp - 2 * RS, half = RS - 2;
        if (s < half) { r = s + 1;        c = 0; }
        else          { r = s - half + 1; c = RS - 1; }
    }
    uint4 z = {0u, 0u, 0u, 0u};
    *(uint4*)&buf[((size_t)pl * RS * RS + r * RS + c) * CI + q * 8] = z;
}

__global__ __launch_bounds__(256)
void att_finalize(const float* __restrict__ score, float* __restrict__ out)
{
    int idx = blockIdx.x * 256 + threadIdx.x;
    if (idx >= 2 * 36864) return;
    int b = idx / 36864, r = idx % 36864;
    int y = r / 192, x = r % 192;
    int i_lo = (y >= 24) ? (y - 12) / 12 : 0;
    int i_hi = min(14, y / 12);
    int j_lo = (x >= 24) ? (x - 12) / 12 : 0;
    int j_hi = min(14, x / 12);
    float s = 0.f; int cnt = 0;
    for (int i = i_lo; i <= i_hi; ++i)
        for (int j = j_lo; j <= j_hi; ++j) {
            s += score[(((size_t)b * 15 + i) * 15 + j) * 576 + (y - 12 * i) * 24 + (x - 12 * j)];
            ++cnt;
        }
    out[idx] = s / (float)cnt;
}

// ---------------------------------------------------------------------------
extern "C" void kernel_launch(void* const* d_in, const int* in_sizes, int n_in,
                              void* d_out, int out_size, void* d_ws, size_t ws_size,
                              hipStream_t stream)
{
    const float* src = (const float*)d_in[0];
    const float* tgt = (const float*)d_in[1];
    const float* W1  = (const float*)d_in[2];  const float* b1  = (const float*)d_in[3];
    const float* W2  = (const float*)d_in[4];  const float* b2  = (const float*)d_in[5];
    const float* W3  = (const float*)d_in[6];  const float* b3  = (const float*)d_in[7];
    const float* Wr1 = (const float*)d_in[8];  const float* br1 = (const float*)d_in[9];
    const float* Wr2 = (const float*)d_in[10]; const float* br2 = (const float*)d_in[11];
    const float* Wr3 = (const float*)d_in[12]; const float* br3 = (const float*)d_in[13];
    float* out = (float*)d_out;

    // ---- fixed workspace (halves) ----
    _Float16* ws = (_Float16*)d_ws;
    size_t o = 0;
    _Float16* X16i = ws + o; o += (size_t)2 * 194 * 194 * 128;
    _Float16* W1h  = ws + o; o += (size_t)512 * 9 * 128;
    _Float16* W2h  = ws + o; o += (size_t)256 * 9 * 512;
    _Float16* Wr1h = ws + o; o += (size_t)512 * 9 * 128;
    _Float16* Wr2h = ws + o; o += (size_t)64 * 9 * 512;
    _Float16* W3p  = ws + o; o += (size_t)16 * 9 * 256;
    _Float16* Wr3p = ws + o; o += (size_t)16 * 9 * 64;
    float*    score = (float*)(ws + o); o += 2 * 259200;
    const size_t fixed_h = o;

    // ---- adaptive patch chunking (no P1: conv1 reads the image, MODE0) ----
    const size_t per_patch_h = (size_t)676 * (512 + 256);        // 519,168
    const size_t regA_h = (size_t)2 * 194 * 194 * 512;
    const size_t regB_h = (size_t)2 * 194 * 194 * 64;
    size_t h_avail = ws_size / 2;
    int P = 50;
    {
        size_t n450 = 450 * per_patch_h; if (n450 < regA_h + regB_h) n450 = regA_h + regB_h;
        size_t n150 = 150 * per_patch_h; if (n150 < regA_h + regB_h) n150 = regA_h + regB_h;
        if (h_avail >= fixed_h + n450)      P = 450;
        else if (h_avail >= fixed_h + n150) P = 150;
    }
    const int nchunks = 450 / P;

    _Float16* D1 = ws + fixed_h;
    _Float16* D2 = D1 + (size_t)P * 676 * 512;

    // ---- precompute fp16 operands ----
    ring_zero<<<(2 * 772 * 16 + 255) / 256, 256, 0, stream>>>(X16i, 2, 194, 128);
    build_x16i<<<4608, 256, 0, stream>>>(src, tgt, X16i);
    cvt_w<<<2304, 256, 0, stream>>>(W1,  W1h,  512, 128);
    cvt_w<<<4608, 256, 0, stream>>>(W2,  W2h,  256, 512);
    cvt_w<<<2304, 256, 0, stream>>>(Wr1, Wr1h, 512, 128);
    cvt_w<<<1152, 256, 0, stream>>>(Wr2, Wr2h, 64,  512);
    cvt_pad16<<<(16 * 9 * 256 + 255) / 256, 256, 0, stream>>>(W3,  W3p,  256);
    cvt_pad16<<<(16 * 9 * 64  + 255) / 256, 256, 0, stream>>>(Wr3, Wr3p, 64);

    // ---- attention path ----
    ring_zero<<<(P * 100 * 64 + 255) / 256, 256, 0, stream>>>(D1, P, 26, 512);
    ring_zero<<<(P * 100 * 32 + 255) / 256, 256, 0, stream>>>(D2, P, 26, 256);
    for (int c = 0; c < nchunks; ++c) {
        int p0 = c * P;
        // conv1: 128->512 from padded image (MODE0), full-patch block, NC=8
        mfma_conv<12, 3, 0><<<swiz_grid(P, 8, 1), 768, 0, stream>>>(
            X16i, W1h, b1, D1, 128, 512, 194, 26, P, 8, 1, p0);
        // conv2: 512->256 (MODE1), full-patch block, NC=4
        mfma_conv<12, 3, 1><<<swiz_grid(P, 4, 1), 768, 0, stream>>>(
            D1, W2h, b2, D2, 512, 256, 26, 26, P, 4, 1, 0);
        // score: sigmoid, px-split x3
        mfma_score<1, 1, 3><<<P * 3, 256, 0, stream>>>(
            D2, W3p, b3, score + (size_t)p0 * 576, 256, 26, P, 3);
    }
    att_finalize<<<288, 256, 0, stream>>>(score, out + 73728);

    // ---- registration path (aliases chunk region; att chain complete) ----
    {
        _Float16* A1 = ws + fixed_h;
        _Float16* A2 = A1 + ((P >= 150) ? regA_h : (size_t)194 * 194 * 512);
        if (P >= 150) {
            ring_zero<<<(2 * 772 * 64 + 255) / 256, 256, 0, stream>>>(A1, 2, 194, 512);
            ring_zero<<<(2 * 772 * 8  + 255) / 256, 256, 0, stream>>>(A2, 2, 194, 64);
            mfma_conv<12, 3, 2><<<swiz_grid(128, 8, 1), 768, 0, stream>>>(
                X16i, Wr1h, br1, A1, 128, 512, 194, 194, 128, 8, 1, 0);
            mfma_conv<6, 3, 2><<<swiz_grid(128, 1, 2), 384, 0, stream>>>(
                A1, Wr2h, br2, A2, 512, 64, 194, 194, 128, 1, 2, 0);
            mfma_score<2, 2, 3><<<128 * 3, 256, 0, stream>>>(
                A2, Wr3p, br3, out, 64, 194, 128, 3);
        } else {
            for (int b = 0; b < 2; ++b) {
                ring_zero<<<(772 * 64 + 255) / 256, 256, 0, stream>>>(A1, 1, 194, 512);
                ring_zero<<<(772 * 8  + 255) / 256, 256, 0, stream>>>(A2, 1, 194, 64);
                mfma_conv<12, 3, 2><<<swiz_grid(64, 8, 1), 768, 0, stream>>>(
                    X16i + (size_t)b * 194 * 194 * 128, Wr1h, br1, A1,
                    128, 512, 194, 194, 64, 8, 1, 0);
                mfma_conv<6, 3, 2><<<swiz_grid(64, 1, 2), 384, 0, stream>>>(
                    A1, Wr2h, br2, A2, 512, 64, 194, 194, 64, 1, 2, 0);
                mfma_score<2, 2, 3><<<64 * 3, 256, 0, stream>>>(
                    A2, Wr3p, br3, out + (size_t)b * 36864, 64, 194, 64, 3);
            }
        }
    }
}

// Round 4
// 2211.376 us; speedup vs baseline: 1.8079x; 1.2477x over previous
//
#include <hip/hip_runtime.h>
#include <cmath>

typedef _Float16 half8  __attribute__((ext_vector_type(8)));
typedef _Float16 half4v __attribute__((ext_vector_type(4)));
typedef float    float4v __attribute__((ext_vector_type(4)));

// ---------------------------------------------------------------------------
// MFMA conv3x3 (SAME), fp16 in / fp32 acc / fp16 out (relu).
// R13: R0 tile restored (MT=8/NT=3, 4 waves, co-tile 128, NC as R0) — traffic
// model: per work unit a-LDS=36/NT, b-VMEM=36/MT; R0's 12+4.5 B is optimal
// under the 96-AGPR acc ceiling (R10/R11/R12 all regressed by raising b to
// 9 B/work). R0's loss was PHASE SERIALIZATION: 73.7 KB stage burst + full
// vmcnt(0) drain per K-step, unhideable at 2 waves/SIMD.
// Fix: dy-phase software pipeline (3 taps/phase), sW ping-pong 2x24.6 KB:
//   phase i: issue stage(i+1) -> s_waitcnt vmcnt(6) [counted, NEVER 0 in
//   loop - T4] -> s_barrier -> setprio(1) MFMA cluster setprio(0) [T5] ->
//   s_barrier. WAR: buf^1 last read 2 phases back, fenced by trailing
//   barrier. RAW: vmcnt(6) retires all older stage loads. Final phase
//   drains vmcnt(0).
// MODE 0: att conv1 reads padded IMAGE; per-lane edge masks emulate SAME pad.
// MODE 1: patch buffer [NB][26][26][CI]. MODE 2: image, unit = b*64 + tile.
// ---------------------------------------------------------------------------
template<int MT, int NT, int MODE>
__global__ __launch_bounds__(256, 2)
void mfma_conv(const _Float16* __restrict__ in, const _Float16* __restrict__ Wg,
               const float* __restrict__ bias, _Float16* __restrict__ out,
               int CI, int CO, int RSin, int RSout, int NB, int NC, int p0)
{
    constexpr int CHUNKS_PH = 3 * MT * 64;           // 16B chunks per phase buf
    constexpr int STAGE_N   = CHUNKS_PH / 256;       // loads per thread per phase
    __shared__ __align__(16) _Float16 sW[2][CHUNKS_PH * 8];

    const int tid  = threadIdx.x;
    const int wave = tid >> 6;
    const int lane = tid & 63;
    const int ll   = lane & 15;
    const int quad = lane >> 4;

    const int NSUB = NC * (9 / NT);
    const int id   = blockIdx.x;
    const int xcd  = id & 7;
    const int slot = id >> 3;
    const int unit = (slot / NSUB) * 8 + xcd;
    const int rem  = slot % NSUB;
    const int pxb  = rem / NC;
    const int co_t = rem % NC;
    if (unit >= NB) return;
    const int co0 = co_t * (MT * 16);
    const int pbase = pxb * (NT * 64) + wave * (NT * 16);

    size_t in_base, out_base;
    int TY = 0, TX = 0;
    int b_off[NT], edge[NT];
    if (MODE == 0) {
        int pat = p0 + unit;
        int bb = pat / 225, remp = pat % 225;
        int pi = remp / 15, pj = remp % 15;
        in_base  = (size_t)bb * RSin * RSin * CI;
        out_base = (size_t)unit * 676 * CO;
        #pragma unroll
        for (int nt = 0; nt < NT; ++nt) {
            int p = pbase + nt * 16 + ll;
            int py = p / 24, px = p % 24;
            b_off[nt] = ((pi * 12 + py) * RSin + (pj * 12 + px)) * CI;
            edge[nt] = (py == 0 ? 1 : 0) | (py == 23 ? 2 : 0)
                     | (px == 0 ? 4 : 0) | (px == 23 ? 8 : 0);
        }
    } else if (MODE == 1) {
        in_base  = (size_t)unit * 676 * CI;
        out_base = (size_t)unit * 676 * CO;
        #pragma unroll
        for (int nt = 0; nt < NT; ++nt) {
            int p = pbase + nt * 16 + ll;
            b_off[nt] = ((p / 24) * RSin + (p % 24)) * CI;
            edge[nt] = 0;
        }
    } else {
        int tile = unit & 63, b = unit >> 6;
        TY = (tile >> 3) * 24; TX = (tile & 7) * 24;
        in_base  = (size_t)b * RSin * RSin * CI;
        out_base = (size_t)b * RSout * RSout * CO;
        #pragma unroll
        for (int nt = 0; nt < NT; ++nt) {
            int p = pbase + nt * 16 + ll;
            b_off[nt] = ((TY + p / 24) * RSin + (TX + p % 24)) * CI;
            edge[nt] = 0;
        }
    }

    // stage one dy-row (3 taps) of weights for [co0, co0+MT*16) x 32 ci
    auto stage = [&](int buf, int ci0, int dy) {
        #pragma unroll
        for (int k = 0; k < STAGE_N; ++k) {
            int c = tid + k * 256;
            int lane_s = c & 63;
            int mtt = c >> 6;
            int mt = mtt % MT, dxl = mtt / MT;          // dxl in [0,3)
            const _Float16* src =
                &Wg[((size_t)(co0 + mt * 16 + (lane_s & 15)) * 9 + (dy * 3 + dxl)) * CI
                    + ci0 + (lane_s >> 4) * 8];
            __builtin_amdgcn_global_load_lds(
                (const __attribute__((address_space(1))) void*)src,
                (__attribute__((address_space(3))) void*)&sW[buf][(size_t)c * 8],
                16, 0, 0);
        }
    };

    float4v acc[MT][NT];
    #pragma unroll
    for (int mt = 0; mt < MT; ++mt)
        #pragma unroll
        for (int nt = 0; nt < NT; ++nt)
            acc[mt][nt] = (float4v){0.f, 0.f, 0.f, 0.f};

    const int phases = (CI >> 5) * 3;
    stage(0, 0, 0);                          // prologue: phase 0 in flight

    int buf = 0, ci0 = 0, dy = 0;
    for (int ph = 0; ph < phases; ++ph) {
        const int dy_n = (dy == 2) ? 0 : dy + 1;
        const int ci_n = (dy == 2) ? ci0 + 32 : ci0;
        if (ph + 1 < phases) {
            stage(buf ^ 1, ci_n, dy_n);
            if (MT == 8) asm volatile("s_waitcnt vmcnt(6)" ::: "memory");
            else         asm volatile("s_waitcnt vmcnt(3)" ::: "memory");
        } else {
            asm volatile("s_waitcnt vmcnt(0)" ::: "memory");
        }
        __builtin_amdgcn_s_barrier();            // buf fully staged, all waves
        __builtin_amdgcn_sched_barrier(0);

        __builtin_amdgcn_s_setprio(1);
        const _Float16* inp = in + in_base + ci0 + quad * 8;
        const int rowoff = dy * RSin * CI;
        #pragma unroll
        for (int dx = 0; dx < 3; ++dx) {
            const int toff = rowoff + dx * CI;
            const int emask = (dy == 0 ? 1 : 0) | (dy == 2 ? 2 : 0)
                            | (dx == 0 ? 4 : 0) | (dx == 2 ? 8 : 0);
            half8 a[MT];
            #pragma unroll
            for (int mt = 0; mt < MT; ++mt)
                a[mt] = *(const half8*)&sW[buf][((dx * MT + mt) * 64 + lane) * 8];
            #pragma unroll
            for (int nt = 0; nt < NT; ++nt) {
                uint4 raw = *(const uint4*)(inp + b_off[nt] + toff);
                if (MODE == 0) {
                    bool z = (edge[nt] & emask) != 0;
                    raw.x = z ? 0u : raw.x;
                    raw.y = z ? 0u : raw.y;
                    raw.z = z ? 0u : raw.z;
                    raw.w = z ? 0u : raw.w;
                }
                half8 b = *(half8*)&raw;
                #pragma unroll
                for (int mt = 0; mt < MT; ++mt)
                    acc[mt][nt] = __builtin_amdgcn_mfma_f32_16x16x32_f16(
                        a[mt], b, acc[mt][nt], 0, 0, 0);
            }
        }
        __builtin_amdgcn_s_setprio(0);
        asm volatile("" ::: "memory");
        __builtin_amdgcn_s_barrier();            // all waves done reading buf
        buf ^= 1; dy = dy_n; ci0 = ci_n;
    }

    // epilogue: bias + relu -> fp16; D layout col=lane&15 (px), row=quad*4+reg
    #pragma unroll
    for (int mt = 0; mt < MT; ++mt) {
        float4v bs = *(const float4v*)&bias[co0 + mt * 16 + quad * 4];
        #pragma unroll
        for (int nt = 0; nt < NT; ++nt) {
            int p = pbase + nt * 16 + ll;
            size_t ooff = out_base
                + (size_t)((TY + p / 24 + 1) * RSout + (TX + p % 24) + 1) * CO
                + co0 + mt * 16 + quad * 4;
            float4v v = acc[mt][nt];
            half4v h;
            h.x = (_Float16)fmaxf(v.x + bs.x, 0.f);
            h.y = (_Float16)fmaxf(v.y + bs.y, 0.f);
            h.z = (_Float16)fmaxf(v.z + bs.z, 0.f);
            h.w = (_Float16)fmaxf(v.w + bs.w, 0.f);
            *(half4v*)(out + ooff) = h;
        }
    }
}

static inline int swiz_grid(int NB, int NC, int PXB) {
    return ((NB + 7) & ~7) * NC * PXB;
}

// ---------------------------------------------------------------------------
// M=1 conv3 via MFMA, CO padded to 16 (rows 1..15 zero). Runtime CI/RSI.
// NT n-tiles per wave, PXB px-blocks: grid = NB*PXB; unit = id/PXB.
// MODE 1: patch buffer [NB][26][26][CI]; ACT 1: sigmoid -> outp[unit*576+p]
// MODE 2: image [b][RSI][RSI][CI];       ACT 2: tanh    -> outp[b*36864+...]
// ---------------------------------------------------------------------------
template<int MODE, int ACT, int NT>
__global__ __launch_bounds__(256, 2)
void mfma_score(const _Float16* __restrict__ in, const _Float16* __restrict__ W16,
                const float* __restrict__ bias, float* __restrict__ outp,
                int CI, int RSI, int NB, int PXB)
{
    __shared__ __align__(16) _Float16 sW[9 * 16 * 32];

    const int tid  = threadIdx.x;
    const int wave = tid >> 6;
    const int lane = tid & 63;
    const int ll   = lane & 15;
    const int quad = lane >> 4;

    const int unit = blockIdx.x / PXB;
    const int pxb  = blockIdx.x % PXB;
    if (unit >= NB) return;
    const int pbase = pxb * (NT * 64) + wave * (NT * 16);

    size_t in_base;
    int ty = 0, tx = 0, bb = 0;
    if (MODE == 2) {
        bb = unit >> 6; int tile = unit & 63; ty = (tile >> 3) * 24; tx = (tile & 7) * 24;
        in_base = (size_t)bb * RSI * RSI * CI;
    } else {
        in_base = (size_t)unit * 676 * CI;
    }

    int b_off[NT];
    #pragma unroll
    for (int nt = 0; nt < NT; ++nt) {
        int p = pbase + nt * 16 + ll;
        b_off[nt] = ((ty + p / 24) * RSI + (tx + p % 24)) * CI;
    }

    float4v acc[NT];
    #pragma unroll
    for (int nt = 0; nt < NT; ++nt) acc[nt] = (float4v){0.f, 0.f, 0.f, 0.f};

    for (int ci0 = 0; ci0 < CI; ci0 += 32) {
        __syncthreads();
        for (int c = tid; c < 9 * 16 * 4; c += 256) {
            int q = c & 3, tco = c >> 2;
            int t = tco >> 4, co = tco & 15;
            *(uint4*)&sW[tco * 32 + q * 8] =
                *(const uint4*)&W16[((size_t)co * 9 + t) * CI + ci0 + q * 8];
        }
        __syncthreads();

        const _Float16* inp = in + in_base + ci0 + quad * 8;
        for (int dy = 0; dy < 3; ++dy)
            for (int dx = 0; dx < 3; ++dx) {
                const int t = dy * 3 + dx;
                const int toff = (dy * RSI + dx) * CI;
                half8 a = *(const half8*)&sW[(t * 16 + ll) * 32 + quad * 8];
                #pragma unroll
                for (int nt = 0; nt < NT; ++nt) {
                    half8 b = *(const half8*)(inp + b_off[nt] + toff);
                    acc[nt] = __builtin_amdgcn_mfma_f32_16x16x32_f16(a, b, acc[nt], 0, 0, 0);
                }
            }
    }

    if (quad == 0) {
        float bv = bias[0];
        #pragma unroll
        for (int nt = 0; nt < NT; ++nt) {
            int p = pbase + nt * 16 + ll;
            float v = acc[nt].x + bv;
            if (ACT == 1) {
                outp[(size_t)unit * 576 + p] = 1.f / (1.f + expf(-v));
            } else {
                int y = ty + p / 24, x = tx + p % 24;
                outp[(size_t)bb * 36864 + y * 192 + x] = tanhf(v);
            }
        }
    }
}

// ---------------------------------------------------------------------------
// helpers
// ---------------------------------------------------------------------------
__global__ __launch_bounds__(256)
void build_x16i(const float* __restrict__ src, const float* __restrict__ tgt,
                _Float16* __restrict__ X)
{
    int idx = blockIdx.x * 256 + threadIdx.x;
    int q = idx & 15, pid = idx >> 4;
    if (pid >= 2 * 36864) return;
    int b = pid / 36864, r = pid % 36864;
    int y = r / 192, x = r % 192;
    half8 h;
    #pragma unroll
    for (int j = 0; j < 8; ++j) {
        int ch = q * 8 + j;
        const float* im = (ch < 64) ? src : tgt;
        h[j] = (_Float16)im[(size_t)(b * 64 + (ch & 63)) * 36864 + r];
    }
    *(half8*)&X[(((size_t)b * 194 + y + 1) * 194 + (x + 1)) * 128 + q * 8] = h;
}

__global__ __launch_bounds__(256)
void cvt_w(const float* __restrict__ src, _Float16* __restrict__ dst, int CO, int CI)
{
    int idx = blockIdx.x * 256 + threadIdx.x;
    if (idx >= CO * 9 * CI) return;
    int ci = idx % CI, t = (idx / CI) % 9, co = idx / (9 * CI);
    dst[idx] = (_Float16)src[((size_t)co * CI + ci) * 9 + t];
}

__global__ __launch_bounds__(256)
void cvt_pad16(const float* __restrict__ src, _Float16* __restrict__ dst, int CI)
{
    int idx = blockIdx.x * 256 + threadIdx.x;
    if (idx >= 16 * 9 * CI) return;
    int ci = idx % CI, t = (idx / CI) % 9, co = idx / (9 * CI);
    dst[idx] = (co == 0) ? (_Float16)src[(size_t)ci * 9 + t] : (_Float16)0.0f;
}

__global__ __launch_bounds__(256)
void ring_zero(_Float16* __restrict__ buf, int npatch, int RS, int CI)
{
    int c8 = CI >> 3;
    int RC = 2 * RS + 2 * (RS - 2);
    int idx = blockIdx.x * 256 + threadIdx.x;
    if (idx >= npatch * RC * c8) return;
    int q = idx % c8, rp = (idx / c8) % RC, pl = idx / (c8 * RC);
    int r, c;
    if (rp < RS)            { r = 0;      c = rp; }
    else if (rp < 2 * RS)   { r = RS - 1; c = rp - RS; }
    else {
        int s = rp - 2 * RS, half = RS - 2;
        if (s < half) { r = s + 1;        c = 0; }
        else          { r = s - half + 1; c = RS - 1; }
    }
    uint4 z = {0u, 0u, 0u, 0u};
    *(uint4*)&buf[((size_t)pl * RS * RS + r * RS + c) * CI + q * 8] = z;
}

__global__ __launch_bounds__(256)
void att_finalize(const float* __restrict__ score, float* __restrict__ out)
{
    int idx = blockIdx.x * 256 + threadIdx.x;
    if (idx >= 2 * 36864) return;
    int b = idx / 36864, r = idx % 36864;
    int y = r / 192, x = r % 192;
    int i_lo = (y >= 24) ? (y - 12) / 12 : 0;
    int i_hi = min(14, y / 12);
    int j_lo = (x >= 24) ? (x - 12) / 12 : 0;
    int j_hi = min(14, x / 12);
    float s = 0.f; int cnt = 0;
    for (int i = i_lo; i <= i_hi; ++i)
        for (int j = j_lo; j <= j_hi; ++j) {
            s += score[(((size_t)b * 15 + i) * 15 + j) * 576 + (y - 12 * i) * 24 + (x - 12 * j)];
            ++cnt;
        }
    out[idx] = s / (float)cnt;
}

// ---------------------------------------------------------------------------
extern "C" void kernel_launch(void* const* d_in, const int* in_sizes, int n_in,
                              void* d_out, int out_size, void* d_ws, size_t ws_size,
                              hipStream_t stream)
{
    const float* src = (const float*)d_in[0];
    const float* tgt = (const float*)d_in[1];
    const float* W1  = (const float*)d_in[2];  const float* b1  = (const float*)d_in[3];
    const float* W2  = (const float*)d_in[4];  const float* b2  = (const float*)d_in[5];
    const float* W3  = (const float*)d_in[6];  const float* b3  = (const float*)d_in[7];
    const float* Wr1 = (const float*)d_in[8];  const float* br1 = (const float*)d_in[9];
    const float* Wr2 = (const float*)d_in[10]; const float* br2 = (const float*)d_in[11];
    const float* Wr3 = (const float*)d_in[12]; const float* br3 = (const float*)d_in[13];
    float* out = (float*)d_out;

    // ---- fixed workspace (halves) ----
    _Float16* ws = (_Float16*)d_ws;
    size_t o = 0;
    _Float16* X16i = ws + o; o += (size_t)2 * 194 * 194 * 128;
    _Float16* W1h  = ws + o; o += (size_t)512 * 9 * 128;
    _Float16* W2h  = ws + o; o += (size_t)256 * 9 * 512;
    _Float16* Wr1h = ws + o; o += (size_t)512 * 9 * 128;
    _Float16* Wr2h = ws + o; o += (size_t)64 * 9 * 512;
    _Float16* W3p  = ws + o; o += (size_t)16 * 9 * 256;
    _Float16* Wr3p = ws + o; o += (size_t)16 * 9 * 64;
    float*    score = (float*)(ws + o); o += 2 * 259200;
    const size_t fixed_h = o;

    // ---- adaptive patch chunking (no P1: conv1 reads the image, MODE0) ----
    const size_t per_patch_h = (size_t)676 * (512 + 256);        // 519,168
    const size_t regA_h = (size_t)2 * 194 * 194 * 512;
    const size_t regB_h = (size_t)2 * 194 * 194 * 64;
    size_t h_avail = ws_size / 2;
    int P = 50;
    {
        size_t n450 = 450 * per_patch_h; if (n450 < regA_h + regB_h) n450 = regA_h + regB_h;
        size_t n150 = 150 * per_patch_h; if (n150 < regA_h + regB_h) n150 = regA_h + regB_h;
        if (h_avail >= fixed_h + n450)      P = 450;
        else if (h_avail >= fixed_h + n150) P = 150;
    }
    const int nchunks = 450 / P;

    _Float16* D1 = ws + fixed_h;
    _Float16* D2 = D1 + (size_t)P * 676 * 512;

    // ---- precompute fp16 operands ----
    ring_zero<<<(2 * 772 * 16 + 255) / 256, 256, 0, stream>>>(X16i, 2, 194, 128);
    build_x16i<<<4608, 256, 0, stream>>>(src, tgt, X16i);
    cvt_w<<<2304, 256, 0, stream>>>(W1,  W1h,  512, 128);
    cvt_w<<<4608, 256, 0, stream>>>(W2,  W2h,  256, 512);
    cvt_w<<<2304, 256, 0, stream>>>(Wr1, Wr1h, 512, 128);
    cvt_w<<<1152, 256, 0, stream>>>(Wr2, Wr2h, 64,  512);
    cvt_pad16<<<(16 * 9 * 256 + 255) / 256, 256, 0, stream>>>(W3,  W3p,  256);
    cvt_pad16<<<(16 * 9 * 64  + 255) / 256, 256, 0, stream>>>(Wr3, Wr3p, 64);

    // ---- attention path ----
    ring_zero<<<(P * 100 * 64 + 255) / 256, 256, 0, stream>>>(D1, P, 26, 512);
    ring_zero<<<(P * 100 * 32 + 255) / 256, 256, 0, stream>>>(D2, P, 26, 256);
    for (int c = 0; c < nchunks; ++c) {
        int p0 = c * P;
        // conv1: 128->512 from padded image (MODE0), MT=8/NT=3, NC=4
        mfma_conv<8, 3, 0><<<swiz_grid(P, 4, 3), 256, 0, stream>>>(
            X16i, W1h, b1, D1, 128, 512, 194, 26, P, 4, p0);
        // conv2: 512->256 (MODE1), MT=8/NT=3, NC=2
        mfma_conv<8, 3, 1><<<swiz_grid(P, 2, 3), 256, 0, stream>>>(
            D1, W2h, b2, D2, 512, 256, 26, 26, P, 2, 0);
        // score: sigmoid, px-split x3
        mfma_score<1, 1, 3><<<P * 3, 256, 0, stream>>>(
            D2, W3p, b3, score + (size_t)p0 * 576, 256, 26, P, 3);
    }
    att_finalize<<<288, 256, 0, stream>>>(score, out + 73728);

    // ---- registration path (aliases chunk region; att chain complete) ----
    {
        _Float16* A1 = ws + fixed_h;
        _Float16* A2 = A1 + ((P >= 150) ? regA_h : (size_t)194 * 194 * 512);
        if (P >= 150) {
            ring_zero<<<(2 * 772 * 64 + 255) / 256, 256, 0, stream>>>(A1, 2, 194, 512);
            ring_zero<<<(2 * 772 * 8  + 255) / 256, 256, 0, stream>>>(A2, 2, 194, 64);
            mfma_conv<8, 3, 2><<<swiz_grid(128, 4, 3), 256, 0, stream>>>(
                X16i, Wr1h, br1, A1, 128, 512, 194, 194, 128, 4, 0);
            mfma_conv<4, 3, 2><<<swiz_grid(128, 1, 3), 256, 0, stream>>>(
                A1, Wr2h, br2, A2, 512, 64, 194, 194, 128, 1, 0);
            mfma_score<2, 2, 3><<<128 * 3, 256, 0, stream>>>(
                A2, Wr3p, br3, out, 64, 194, 128, 3);
        } else {
            for (int b = 0; b < 2; ++b) {
                ring_zero<<<(772 * 64 + 255) / 256, 256, 0, stream>>>(A1, 1, 194, 512);
                ring_zero<<<(772 * 8  + 255) / 256, 256, 0, stream>>>(A2, 1, 194, 64);
                mfma_conv<8, 3, 2><<<swiz_grid(64, 4, 3), 256, 0, stream>>>(
                    X16i + (size_t)b * 194 * 194 * 128, Wr1h, br1, A1,
                    128, 512, 194, 194, 64, 4, 0);
                mfma_conv<4, 3, 2><<<swiz_grid(64, 1, 3), 256, 0, stream>>>(
                    A1, Wr2h, br2, A2, 512, 64, 194, 194, 64, 1, 0);
                mfma_score<2, 2, 3><<<64 * 3, 256, 0, stream>>>(
                    A2, Wr3p, br3, out + (size_t)b * 36864, 64, 194, 64, 3);
            }
        }
    }
}